// Round 1
// baseline (6528.143 us; speedup 1.0000x reference)
//
#include <hip/hip_runtime.h>

// Problem constants (fixed by the reference)
#define D_   8
#define Q_   1024
#define DB_  32768
#define F_   64
#define NB_  128      // num_buckets = num_neighbors
#define BS_  256      // bucket_size = DB/NB
#define NT_  (Q_*D_*NB_)   // 1,048,576 (q,d,j) triples
#define SPLIT_ 4      // split of the b-range across blocks (split-K style)
#define QT_  32       // queries per block
#define MARGIN_ 4e-3f // fp32 top-2 gap below which we escalate to fp64 exact path

// ---------------------------------------------------------------------------
// K1: fp32 scan. Block = (q-tile of 32, dataset d, b-range of 64).
// 256 threads = 8 qg (4 q each) x 32 jg (4 j each); per-thread 4x4 register
// tile of dot-product accumulators; keys staged per-b in LDS (pad +4 floats
// to break the 64-float row-stride bank conflict). Tracks per-(q,j) top-2
// (max value+index, 2nd max value) over its b-range; writes partials.
// ---------------------------------------------------------------------------
__global__ __launch_bounds__(256) void k_scan(const float* __restrict__ query,
                                              const float* __restrict__ key_db,
                                              float* __restrict__ m1p,
                                              float* __restrict__ m2p,
                                              int*   __restrict__ b1p)
{
    __shared__ float qs[QT_][F_];        // 8 KB
    __shared__ float ks[NB_][F_ + 4];    // 34 KB, padded
    const int d    = blockIdx.y;
    const int q0   = blockIdx.x * QT_;
    const int half = blockIdx.z;
    const int tid  = threadIdx.x;

    // stage query tile (rows are 256B, stride D_*F_ floats in global)
    for (int i = tid; i < QT_ * F_ / 4; i += 256) {
        int qq = i >> 4, c = i & 15;
        *reinterpret_cast<float4*>(&qs[qq][c * 4]) =
            *reinterpret_cast<const float4*>(query + ((size_t)(q0 + qq) * D_ + d) * F_ + c * 4);
    }

    const int qg = tid >> 5;   // 0..7  -> q = q0 + qg*4 + r
    const int jg = tid & 31;   // 0..31 -> j = jg + 32*s
    float m1[16], m2[16];
    int   b1[16];
#pragma unroll
    for (int i = 0; i < 16; ++i) { m1[i] = -3e38f; m2[i] = -3e38f; b1[i] = 0; }

    const int bs_per = BS_ / SPLIT_;     // 64
    const int bstart = half * bs_per;
    const float* kbase = key_db + (size_t)d * DB_ * F_;

    for (int bb = 0; bb < bs_per; ++bb) {
        const int b = bstart + bb;
        __syncthreads();
        // stage the 128 key rows n = b*128 + j (32 KB contiguous in global)
        const float4* src = reinterpret_cast<const float4*>(kbase + (size_t)b * NB_ * F_);
        for (int i = tid; i < NB_ * F_ / 4; i += 256) {
            int j = i >> 4, c = i & 15;
            *reinterpret_cast<float4*>(&ks[j][c * 4]) = src[i];
        }
        __syncthreads();

        float acc[16];
#pragma unroll
        for (int i = 0; i < 16; ++i) acc[i] = 0.f;
#pragma unroll
        for (int kc = 0; kc < 16; ++kc) {
            float4 kk[4], qv[4];
#pragma unroll
            for (int s = 0; s < 4; ++s)
                kk[s] = *reinterpret_cast<const float4*>(&ks[jg + 32 * s][kc * 4]);
#pragma unroll
            for (int r = 0; r < 4; ++r)
                qv[r] = *reinterpret_cast<const float4*>(&qs[qg * 4 + r][kc * 4]);
#pragma unroll
            for (int r = 0; r < 4; ++r)
#pragma unroll
                for (int s = 0; s < 4; ++s)
                    acc[r * 4 + s] += qv[r].x * kk[s].x + qv[r].y * kk[s].y
                                    + qv[r].z * kk[s].z + qv[r].w * kk[s].w;
        }
#pragma unroll
        for (int i = 0; i < 16; ++i) {
            float v = acc[i];
            if (v > m1[i]) { m2[i] = m1[i]; m1[i] = v; b1[i] = b; }
            else if (v > m2[i]) m2[i] = v;
        }
    }

    // write partials at p = half*NT + t, t = (q*D + d)*NB + j
#pragma unroll
    for (int r = 0; r < 4; ++r)
#pragma unroll
        for (int s = 0; s < 4; ++s) {
            int i = r * 4 + s;
            int q = q0 + qg * 4 + r;
            int j = jg + 32 * s;
            size_t p = (size_t)half * NT_ + ((size_t)(q * D_ + d) * NB_ + j);
            m1p[p] = m1[i];
            m2p[p] = m2[i];
            b1p[p] = b1[i];
        }
}

// ---------------------------------------------------------------------------
// Merge split-b partials -> final argmax index + near-tie flag list.
// ---------------------------------------------------------------------------
__global__ void k_merge(const float* __restrict__ m1p, const float* __restrict__ m2p,
                        const int* __restrict__ b1p, int* __restrict__ idx0,
                        int* __restrict__ flag_cnt, int* __restrict__ flag_list)
{
    int t = blockIdx.x * 256 + threadIdx.x;
    if (t >= NT_) return;
    float m1 = -3e38f, m2 = -3e38f;
    int i1 = 0;
#pragma unroll
    for (int h = 0; h < SPLIT_; ++h) {
        float a    = m1p[(size_t)h * NT_ + t];
        float bsec = m2p[(size_t)h * NT_ + t];
        int   ib   = b1p[(size_t)h * NT_ + t];
        if (a > m1) { m2 = m1; m1 = a; i1 = ib; }
        else if (a > m2) m2 = a;
        if (bsec > m2) m2 = bsec;
    }
    idx0[t] = i1;
    if (m2 >= m1 - MARGIN_) {
        int pos = atomicAdd(flag_cnt, 1);
        if (pos < NT_) flag_list[pos] = t;
    }
}

// ---------------------------------------------------------------------------
// K2: gather. Writes all 512 MB of output (hard-argmax rows).
// float4 per thread; keys half then values half.
// ---------------------------------------------------------------------------
__global__ void k_gather(const float* __restrict__ key_db, const float* __restrict__ value_db,
                         const int* __restrict__ idx0, float4* __restrict__ out)
{
    const int total = NT_ * 16 * 2;   // 33,554,432 float4
    for (int e = blockIdx.x * 256 + threadIdx.x; e < total; e += gridDim.x * 256) {
        int half = e >> 24;           // 2^24 float4 per output half
        int rem  = e & 0xFFFFFF;
        int t  = rem >> 4;            // (q*D+d)*NB + j
        int fc = rem & 15;
        int j = t & 127;
        int d = (t >> 7) & 7;
        int b = idx0[t];
        const float* db = half ? value_db : key_db;
        int n = b * NB_ + j;
        out[e] = *reinterpret_cast<const float4*>(db + ((size_t)d * DB_ + n) * F_ + fc * 4);
    }
}

// ---------------------------------------------------------------------------
// K3: exact fp64 fix-up for flagged near-tie triples. One wave per triple.
// Recomputes all 256 scores in fp64, full softmax(x*1e6), blends rows,
// overwrites the two output rows. No LDS / no __syncthreads (waves diverge).
// ---------------------------------------------------------------------------
__global__ void k_fix(const float* __restrict__ query, const float* __restrict__ key_db,
                      const float* __restrict__ value_db, const int* __restrict__ flag_cnt,
                      const int* __restrict__ flag_list, float* __restrict__ out)
{
    int cnt = *flag_cnt;
    if (cnt > NT_) cnt = NT_;
    int gw   = (blockIdx.x * blockDim.x + threadIdx.x) >> 6;
    int lane = threadIdx.x & 63;
    int nw   = (gridDim.x * blockDim.x) >> 6;

    for (int w = gw; w < cnt; w += nw) {
        int t = flag_list[w];
        int j = t & 127, d = (t >> 7) & 7, qi = t >> 10;
        const float* qrow = query + ((size_t)qi * D_ + d) * F_;
        const float* kb = key_db + (size_t)d * DB_ * F_;
        const float* vb = value_db + (size_t)d * DB_ * F_;

        // phase 1: lane holds b = lane*4 + i
        double sv[4];
#pragma unroll
        for (int i = 0; i < 4; ++i) {
            int b = lane * 4 + i;
            const float* krow = kb + ((size_t)b * NB_ + j) * F_;
            double a = 0.0;
            for (int k2 = 0; k2 < F_; ++k2) a += (double)qrow[k2] * (double)krow[k2];
            sv[i] = a;
        }
        double m = fmax(fmax(sv[0], sv[1]), fmax(sv[2], sv[3]));
        for (int off = 32; off; off >>= 1) m = fmax(m, __shfl_xor(m, off));
        double ev[4];
        double es = 0.0;
#pragma unroll
        for (int i = 0; i < 4; ++i) { ev[i] = exp((sv[i] - m) * 1e6); es += ev[i]; }
        for (int off = 32; off; off >>= 1) es += __shfl_xor(es, off);
        double inv = 1.0 / es;
#pragma unroll
        for (int i = 0; i < 4; ++i) ev[i] *= inv;

        // phase 2: lane = feature f; blend rows with nonzero weights
        double ak = 0.0, av = 0.0;
        for (int src = 0; src < 64; ++src) {
#pragma unroll
            for (int i = 0; i < 4; ++i) {
                double wv = __shfl(ev[i], src);
                if (wv != 0.0) {
                    int b = src * 4 + i;
                    size_t o = ((size_t)b * NB_ + j) * F_ + lane;
                    ak += wv * (double)kb[o];
                    av += wv * (double)vb[o];
                }
            }
        }
        out[(size_t)t * F_ + lane] = (float)ak;
        out[(size_t)NT_ * F_ + (size_t)t * F_ + lane] = (float)av;
    }
}

// ---------------------------------------------------------------------------
extern "C" void kernel_launch(void* const* d_in, const int* in_sizes, int n_in,
                              void* d_out, int out_size, void* d_ws, size_t ws_size,
                              hipStream_t stream)
{
    const float* query    = (const float*)d_in[0];
    const float* key_db   = (const float*)d_in[1];
    const float* value_db = (const float*)d_in[2];
    float* out = (float*)d_out;

    // ws layout (~8.4 MB): idx0[NT] | flag_cnt (256B-aligned slot) | flag_list[NT]
    int* idx0      = (int*)d_ws;
    int* flag_cnt  = (int*)((char*)d_ws + (size_t)NT_ * 4);
    int* flag_list = (int*)((char*)d_ws + (size_t)NT_ * 4 + 256);

    // Split-b partials parked in the (not-yet-written) front of d_out: 48 MB.
    // k_gather later overwrites every byte of d_out, so this is scratch-safe.
    float* m1p = out;                                   // SPLIT_*NT_ floats
    float* m2p = out + (size_t)SPLIT_ * NT_;            // SPLIT_*NT_ floats
    int*   b1p = (int*)(out + (size_t)2 * SPLIT_ * NT_);// SPLIT_*NT_ ints

    hipMemsetAsync(flag_cnt, 0, 4, stream);

    dim3 g1(Q_ / QT_, D_, SPLIT_);                      // 32 x 8 x 4 = 1024 blocks
    k_scan <<<g1, 256, 0, stream>>>(query, key_db, m1p, m2p, b1p);
    k_merge<<<(NT_ + 255) / 256, 256, 0, stream>>>(m1p, m2p, b1p, idx0, flag_cnt, flag_list);
    k_gather<<<2048, 256, 0, stream>>>(key_db, value_db, idx0, (float4*)d_out);
    k_fix  <<<256, 256, 0, stream>>>(query, key_db, value_db, flag_cnt, flag_list, out);
}

// Round 2
// 641.192 us; speedup vs baseline: 10.1813x; 10.1813x over previous
//
#include <hip/hip_runtime.h>

// Problem constants (fixed by the reference)
#define D_   8
#define Q_   1024
#define DB_  32768
#define F_   64
#define NB_  128      // num_buckets = num_neighbors
#define BS_  256      // bucket_size = DB/NB
#define NT_  (Q_*D_*NB_)   // 1,048,576 (q,d,j) triples
#define SPLIT_ 2      // split of the b-range across blocks
#define MARGIN_ 4e-3f // top-2 gap below which we escalate to fp64 exact path
                      // (split-bf16 score err <= ~5e-4, so margin still safe)

typedef __attribute__((ext_vector_type(16))) float  f32x16;
typedef __attribute__((ext_vector_type(8)))  short  short8;
typedef __attribute__((ext_vector_type(4)))  short  short4v;
typedef __attribute__((ext_vector_type(8)))  __bf16 bf16x8;

static __device__ __forceinline__ short f2bf(float x) {   // RNE float->bf16
    unsigned u = __float_as_uint(x);
    u += 0x7fffu + ((u >> 16) & 1u);
    return (short)(u >> 16);
}
static __device__ __forceinline__ float bf2f(short h) {
    return __uint_as_float(((unsigned)(unsigned short)h) << 16);
}
static __device__ __forceinline__ f32x16 mfma32(short8 a, short8 b, f32x16 c) {
    return __builtin_amdgcn_mfma_f32_32x32x16_bf16(
        __builtin_bit_cast(bf16x8, a), __builtin_bit_cast(bf16x8, b), c, 0, 0, 0);
}

// ---------------------------------------------------------------------------
// Split-bf16 conversion: x = hi + lo, both bf16 (RNE). Keys: elementwise.
// ---------------------------------------------------------------------------
__global__ void k_conv(const float* __restrict__ src, short* __restrict__ hi,
                       short* __restrict__ lo, int n4)
{
    for (int i = blockIdx.x * 256 + threadIdx.x; i < n4; i += gridDim.x * 256) {
        float4 v = ((const float4*)src)[i];
        short4v h, l;
        h.x = f2bf(v.x); l.x = f2bf(v.x - bf2f(h.x));
        h.y = f2bf(v.y); l.y = f2bf(v.y - bf2f(h.y));
        h.z = f2bf(v.z); l.z = f2bf(v.z - bf2f(h.z));
        h.w = f2bf(v.w); l.w = f2bf(v.w - bf2f(h.w));
        *(short4v*)(hi + (size_t)i * 4) = h;
        *(short4v*)(lo + (size_t)i * 4) = l;
    }
}

// Query conversion with (Q,D,F) -> (D,Q,F) transpose.
__global__ void k_convq(const float* __restrict__ q, short* __restrict__ hi,
                        short* __restrict__ lo)
{
    int i = blockIdx.x * 256 + threadIdx.x;   // exactly Q_*D_*F_/4 threads
    int c = i & 15, d = (i >> 4) & 7, qq = i >> 7;
    float4 v = *(const float4*)(q + ((size_t)qq * D_ + d) * F_ + c * 4);
    short4v h, l;
    h.x = f2bf(v.x); l.x = f2bf(v.x - bf2f(h.x));
    h.y = f2bf(v.y); l.y = f2bf(v.y - bf2f(h.y));
    h.z = f2bf(v.z); l.z = f2bf(v.z - bf2f(h.z));
    h.w = f2bf(v.w); l.w = f2bf(v.w - bf2f(h.w));
    size_t o = ((size_t)d * Q_ + qq) * F_ + c * 4;
    *(short4v*)(hi + o) = h;
    *(short4v*)(lo + o) = l;
}

// ---------------------------------------------------------------------------
// K1: MFMA scan. Block = 64q x 64j, 4 waves each owning one 32x32 tile.
// Per b-step: 12 x mfma_f32_32x32x16_bf16 (3 split-passes x 4 ksteps) per
// wave; K tile (hi+lo) double-buffered in LDS, rows padded +8 bf16 so the
// stride-144B layout is bank-balanced for ds_read_b128/ds_write_b128.
// Q frags hoisted to registers. Top-2 tracked per lane over 16 (q,j) pairs.
// ---------------------------------------------------------------------------
__global__ __launch_bounds__(256, 2) void k_scan_mfma(
    const short* __restrict__ khi, const short* __restrict__ klo,
    const short* __restrict__ qhi, const short* __restrict__ qlo,
    float* __restrict__ m1p, float* __restrict__ m2p, int* __restrict__ b1p)
{
    __shared__ short kbuf[2][2][64][72];   // [buf][part][row][col] = 36 KB
    const int tid = threadIdx.x;
    // XCD-bijective swizzle (512 = 8 XCD x 64): same-key q-blocks share an XCD.
    const int w    = ((blockIdx.x & 7) << 6) | (blockIdx.x >> 3);
    const int qi   = w & 15;
    const int ji   = (w >> 4) & 1;
    const int d    = (w >> 5) & 7;
    const int half = (w >> 8) & 1;
    const int q0 = qi * 64, j0 = ji * 64;
    const int wv = tid >> 6, lane = tid & 63;
    const int qg = wv >> 1, jg = wv & 1;
    const int lrow = lane & 31, kg = lane >> 5;

    // hoist Q fragments (A-operand): row = l&31, 8 bf16 at k = ks*16 + (l>>5)*8
    short8 qh[4], ql[4];
    {
        const size_t qoff = ((size_t)d * Q_ + q0 + qg * 32 + lrow) * F_ + kg * 8;
#pragma unroll
        for (int ks = 0; ks < 4; ++ks) {
            qh[ks] = *(const short8*)(qhi + qoff + ks * 16);
            ql[ks] = *(const short8*)(qlo + qoff + ks * 16);
        }
    }

    float m1[16], m2[16]; int b1[16];
#pragma unroll
    for (int r = 0; r < 16; ++r) { m1[r] = -3e38f; m2[r] = -3e38f; b1[r] = 0; }

    const int bstart = half * (BS_ / SPLIT_);
    const int bend   = bstart + (BS_ / SPLIT_);
    const size_t kslab = (size_t)d * DB_ * F_;
    const int sr = tid >> 3, sc = (tid & 7) * 8;   // staging dest row/col

    { // prologue: stage tile bstart into buf 0
        const size_t off = kslab + ((size_t)bstart * NB_ + j0) * F_;
        short8 h0 = *(const short8*)(khi + off + (size_t)tid * 8);
        short8 h1 = *(const short8*)(khi + off + (size_t)(tid + 256) * 8);
        short8 l0 = *(const short8*)(klo + off + (size_t)tid * 8);
        short8 l1 = *(const short8*)(klo + off + (size_t)(tid + 256) * 8);
        *(short8*)&kbuf[0][0][sr][sc]      = h0;
        *(short8*)&kbuf[0][0][sr + 32][sc] = h1;
        *(short8*)&kbuf[0][1][sr][sc]      = l0;
        *(short8*)&kbuf[0][1][sr + 32][sc] = l1;
    }
    __syncthreads();

    const int jrow = jg * 32 + lrow;
    int cur = 0;
    for (int b = bstart; b < bend; ++b) {
        short8 h0, h1, l0, l1;
        const bool more = (b + 1 < bend);
        if (more) {   // issue next-tile global loads early (hide under MFMA)
            const size_t off = kslab + ((size_t)(b + 1) * NB_ + j0) * F_;
            h0 = *(const short8*)(khi + off + (size_t)tid * 8);
            h1 = *(const short8*)(khi + off + (size_t)(tid + 256) * 8);
            l0 = *(const short8*)(klo + off + (size_t)tid * 8);
            l1 = *(const short8*)(klo + off + (size_t)(tid + 256) * 8);
        }
        short8 kh[4], kl[4];
#pragma unroll
        for (int ks = 0; ks < 4; ++ks) {
            kh[ks] = *(const short8*)&kbuf[cur][0][jrow][ks * 16 + kg * 8];
            kl[ks] = *(const short8*)&kbuf[cur][1][jrow][ks * 16 + kg * 8];
        }
        f32x16 c0 = {0,0,0,0,0,0,0,0,0,0,0,0,0,0,0,0};
        f32x16 c1 = {0,0,0,0,0,0,0,0,0,0,0,0,0,0,0,0};
#pragma unroll
        for (int ks = 0; ks < 4; ++ks) c0 = mfma32(qh[ks], kh[ks], c0);
#pragma unroll
        for (int ks = 0; ks < 4; ++ks) c1 = mfma32(qh[ks], kl[ks], c1);
#pragma unroll
        for (int ks = 0; ks < 4; ++ks) c0 = mfma32(ql[ks], kh[ks], c0);
#pragma unroll
        for (int r = 0; r < 16; ++r) {
            float v = c0[r] + c1[r];
            if (v > m1[r]) { m2[r] = m1[r]; m1[r] = v; b1[r] = b; }
            else if (v > m2[r]) m2[r] = v;
        }
        if (more) {
            const int nb = cur ^ 1;
            *(short8*)&kbuf[nb][0][sr][sc]      = h0;
            *(short8*)&kbuf[nb][0][sr + 32][sc] = h1;
            *(short8*)&kbuf[nb][1][sr][sc]      = l0;
            *(short8*)&kbuf[nb][1][sr + 32][sc] = l1;
        }
        __syncthreads();
        cur ^= 1;
    }

    // write partials; C layout (verified): col=lane&31, row=(r&3)+8*(r>>2)+4*kg
#pragma unroll
    for (int r = 0; r < 16; ++r) {
        const int q = q0 + qg * 32 + 4 * kg + (r & 3) + 8 * (r >> 2);
        const size_t t = (((size_t)q * D_ + d) << 7) + j0 + jrow;
        const size_t p = (size_t)half * NT_ + t;
        m1p[p] = m1[r]; m2p[p] = m2[r]; b1p[p] = b1[r];
    }
}

// ---------------------------------------------------------------------------
// Merge split-b partials -> final argmax index + near-tie flag list.
// ---------------------------------------------------------------------------
__global__ void k_merge(const float* __restrict__ m1p, const float* __restrict__ m2p,
                        const int* __restrict__ b1p, int* __restrict__ idx0,
                        int* __restrict__ flag_cnt, int* __restrict__ flag_list)
{
    int t = blockIdx.x * 256 + threadIdx.x;
    if (t >= NT_) return;
    float m1 = -3e38f, m2 = -3e38f;
    int i1 = 0;
#pragma unroll
    for (int h = 0; h < SPLIT_; ++h) {
        float a    = m1p[(size_t)h * NT_ + t];
        float bsec = m2p[(size_t)h * NT_ + t];
        int   ib   = b1p[(size_t)h * NT_ + t];
        if (a > m1) { m2 = m1; m1 = a; i1 = ib; }
        else if (a > m2) m2 = a;
        if (bsec > m2) m2 = bsec;
    }
    idx0[t] = i1;
    if (m2 >= m1 - MARGIN_) {
        int pos = atomicAdd(flag_cnt, 1);
        if (pos < NT_) flag_list[pos] = t;
    }
}

// ---------------------------------------------------------------------------
// K2: gather. Writes all 512 MB of output (hard-argmax rows).
// ---------------------------------------------------------------------------
__global__ void k_gather(const float* __restrict__ key_db, const float* __restrict__ value_db,
                         const int* __restrict__ idx0, float4* __restrict__ out)
{
    const int total = NT_ * 16 * 2;   // 33,554,432 float4
    for (int e = blockIdx.x * 256 + threadIdx.x; e < total; e += gridDim.x * 256) {
        int half = e >> 24;
        int rem  = e & 0xFFFFFF;
        int t  = rem >> 4;
        int fc = rem & 15;
        int j = t & 127;
        int d = (t >> 7) & 7;
        int b = idx0[t];
        const float* db = half ? value_db : key_db;
        int n = b * NB_ + j;
        out[e] = *reinterpret_cast<const float4*>(db + ((size_t)d * DB_ + n) * F_ + fc * 4);
    }
}

// ---------------------------------------------------------------------------
// K3: exact fp64 fix-up for flagged near-tie triples. One wave per triple.
// ---------------------------------------------------------------------------
__global__ void k_fix(const float* __restrict__ query, const float* __restrict__ key_db,
                      const float* __restrict__ value_db, const int* __restrict__ flag_cnt,
                      const int* __restrict__ flag_list, float* __restrict__ out)
{
    int cnt = *flag_cnt;
    if (cnt > NT_) cnt = NT_;
    int gw   = (blockIdx.x * blockDim.x + threadIdx.x) >> 6;
    int lane = threadIdx.x & 63;
    int nw   = (gridDim.x * blockDim.x) >> 6;

    for (int w = gw; w < cnt; w += nw) {
        int t = flag_list[w];
        int j = t & 127, d = (t >> 7) & 7, qi = t >> 10;
        const float* qrow = query + ((size_t)qi * D_ + d) * F_;
        const float* kb = key_db + (size_t)d * DB_ * F_;
        const float* vb = value_db + (size_t)d * DB_ * F_;

        double sv[4];
#pragma unroll
        for (int i = 0; i < 4; ++i) {
            int b = lane * 4 + i;
            const float* krow = kb + ((size_t)b * NB_ + j) * F_;
            double a = 0.0;
            for (int k2 = 0; k2 < F_; ++k2) a += (double)qrow[k2] * (double)krow[k2];
            sv[i] = a;
        }
        double m = fmax(fmax(sv[0], sv[1]), fmax(sv[2], sv[3]));
        for (int off = 32; off; off >>= 1) m = fmax(m, __shfl_xor(m, off));
        double ev[4];
        double es = 0.0;
#pragma unroll
        for (int i = 0; i < 4; ++i) { ev[i] = exp((sv[i] - m) * 1e6); es += ev[i]; }
        for (int off = 32; off; off >>= 1) es += __shfl_xor(es, off);
        double inv = 1.0 / es;
#pragma unroll
        for (int i = 0; i < 4; ++i) ev[i] *= inv;

        double ak = 0.0, av = 0.0;
        for (int src = 0; src < 64; ++src) {
#pragma unroll
            for (int i = 0; i < 4; ++i) {
                double wv = __shfl(ev[i], src);
                if (wv != 0.0) {
                    int b = src * 4 + i;
                    size_t o = ((size_t)b * NB_ + j) * F_ + lane;
                    ak += wv * (double)kb[o];
                    av += wv * (double)vb[o];
                }
            }
        }
        out[(size_t)t * F_ + lane] = (float)ak;
        out[(size_t)NT_ * F_ + (size_t)t * F_ + lane] = (float)av;
    }
}

// ---------------------------------------------------------------------------
extern "C" void kernel_launch(void* const* d_in, const int* in_sizes, int n_in,
                              void* d_out, int out_size, void* d_ws, size_t ws_size,
                              hipStream_t stream)
{
    const float* query    = (const float*)d_in[0];
    const float* key_db   = (const float*)d_in[1];
    const float* value_db = (const float*)d_in[2];
    float* out = (float*)d_out;

    // ws layout (~8.4 MB): idx0[NT] | flag_cnt | flag_list[NT]
    int* idx0      = (int*)d_ws;
    int* flag_cnt  = (int*)((char*)d_ws + (size_t)NT_ * 4);
    int* flag_list = (int*)((char*)d_ws + (size_t)NT_ * 4 + 256);

    // Scratch parked in the not-yet-written front of d_out (~94 MB of 512 MB):
    // bf16 hi/lo copies of keys+queries, then split-b partials. k_gather
    // overwrites every byte of d_out afterwards; all reads happen before.
    short* khi = (short*)d_out;                          // 33.5 MB
    short* klo = khi + (size_t)D_ * DB_ * F_;            // 33.5 MB
    short* qhi = klo + (size_t)D_ * DB_ * F_;            // 1 MB
    short* qlo = qhi + (size_t)Q_ * D_ * F_;             // 1 MB
    float* m1p = (float*)(qlo + (size_t)Q_ * D_ * F_);   // 8.4 MB
    float* m2p = m1p + (size_t)SPLIT_ * NT_;             // 8.4 MB
    int*   b1p = (int*)(m2p + (size_t)SPLIT_ * NT_);     // 8.4 MB

    hipMemsetAsync(flag_cnt, 0, 4, stream);

    k_conv     <<<2048, 256, 0, stream>>>(key_db, khi, klo, D_ * DB_ * F_ / 4);
    k_convq    <<<512,  256, 0, stream>>>(query, qhi, qlo);
    k_scan_mfma<<<512,  256, 0, stream>>>(khi, klo, qhi, qlo, m1p, m2p, b1p);
    k_merge    <<<NT_ / 256, 256, 0, stream>>>(m1p, m2p, b1p, idx0, flag_cnt, flag_list);
    k_gather   <<<2048, 256, 0, stream>>>(key_db, value_db, idx0, (float4*)d_out);
    k_fix      <<<256,  256, 0, stream>>>(query, key_db, value_db, flag_cnt, flag_list, out);
}

// Round 3
// 410.690 us; speedup vs baseline: 15.8955x; 1.5613x over previous
//
#include <hip/hip_runtime.h>

// Problem constants (fixed by the reference)
#define D_   8
#define Q_   1024
#define DB_  32768
#define F_   64
#define NB_  128      // num_buckets = num_neighbors
#define BS_  256      // bucket_size = DB/NB
#define NT_  (Q_*D_*NB_)   // 1,048,576 (q,d,j) triples
#define SPLIT_ 4      // split of the b-range across blocks
#define MARGIN_ 4e-3f // top-2 gap below which we escalate to fp64 exact path
                      // (split-bf16 score err <= ~5e-4, so margin still safe)

typedef __attribute__((ext_vector_type(16))) float  f32x16;
typedef __attribute__((ext_vector_type(8)))  short  short8;
typedef __attribute__((ext_vector_type(4)))  short  short4v;
typedef __attribute__((ext_vector_type(8)))  __bf16 bf16x8;

static __device__ __forceinline__ short f2bf(float x) {   // RNE float->bf16
    unsigned u = __float_as_uint(x);
    u += 0x7fffu + ((u >> 16) & 1u);
    return (short)(u >> 16);
}
static __device__ __forceinline__ float bf2f(short h) {
    return __uint_as_float(((unsigned)(unsigned short)h) << 16);
}
static __device__ __forceinline__ f32x16 mfma32(short8 a, short8 b, f32x16 c) {
    return __builtin_amdgcn_mfma_f32_32x32x16_bf16(
        __builtin_bit_cast(bf16x8, a), __builtin_bit_cast(bf16x8, b), c, 0, 0, 0);
}

// ---------------------------------------------------------------------------
// Split-bf16 conversion: x = hi + lo, both bf16 (RNE). Keys: elementwise.
// ---------------------------------------------------------------------------
__global__ void k_conv(const float* __restrict__ src, short* __restrict__ hi,
                       short* __restrict__ lo, int n4)
{
    for (int i = blockIdx.x * 256 + threadIdx.x; i < n4; i += gridDim.x * 256) {
        float4 v = ((const float4*)src)[i];
        short4v h, l;
        h.x = f2bf(v.x); l.x = f2bf(v.x - bf2f(h.x));
        h.y = f2bf(v.y); l.y = f2bf(v.y - bf2f(h.y));
        h.z = f2bf(v.z); l.z = f2bf(v.z - bf2f(h.z));
        h.w = f2bf(v.w); l.w = f2bf(v.w - bf2f(h.w));
        *(short4v*)(hi + (size_t)i * 4) = h;
        *(short4v*)(lo + (size_t)i * 4) = l;
    }
}

// Query conversion with (Q,D,F) -> (D,Q,F) transpose.
__global__ void k_convq(const float* __restrict__ q, short* __restrict__ hi,
                        short* __restrict__ lo)
{
    int i = blockIdx.x * 256 + threadIdx.x;   // exactly Q_*D_*F_/4 threads
    int c = i & 15, d = (i >> 4) & 7, qq = i >> 7;
    float4 v = *(const float4*)(q + ((size_t)qq * D_ + d) * F_ + c * 4);
    short4v h, l;
    h.x = f2bf(v.x); l.x = f2bf(v.x - bf2f(h.x));
    h.y = f2bf(v.y); l.y = f2bf(v.y - bf2f(h.y));
    h.z = f2bf(v.z); l.z = f2bf(v.z - bf2f(h.z));
    h.w = f2bf(v.w); l.w = f2bf(v.w - bf2f(h.w));
    size_t o = ((size_t)d * Q_ + qq) * F_ + c * 4;
    *(short4v*)(hi + o) = h;
    *(short4v*)(lo + o) = l;
}

// ---------------------------------------------------------------------------
// K1: MFMA scan. Block = 64q x 64j, 4 waves each owning one 32x32 tile.
// Per b-step: 12 x mfma_f32_32x32x16_bf16 per wave; K tile (hi+lo)
// double-buffered in LDS (rows padded +8 bf16 -> conflict-free b128).
// Q frags in registers. Branchless top-2 via med3/max (5 VALU per score).
// 4 blocks/CU (LDS 4x36KB=144KB, VGPR<=128) for latency hiding.
// ---------------------------------------------------------------------------
__global__ __launch_bounds__(256, 4) void k_scan_mfma(
    const short* __restrict__ khi, const short* __restrict__ klo,
    const short* __restrict__ qhi, const short* __restrict__ qlo,
    float* __restrict__ m1p, float* __restrict__ m2p, int* __restrict__ b1p)
{
    __shared__ short kbuf[2][2][64][72];   // [buf][part][row][col] = 36 KB
    const int tid = threadIdx.x;
    // XCD swizzle (1024 = 8 XCD x 128): contiguous w per XCD -> same-key
    // q-tiles co-resident on one XCD (bijective: 1024 % 8 == 0).
    const int w    = ((blockIdx.x & 7) << 7) | (blockIdx.x >> 3);
    const int qi   = w & 15;
    const int ji   = (w >> 4) & 1;
    const int d    = (w >> 5) & 7;
    const int half = w >> 8;               // 0..SPLIT_-1
    const int q0 = qi * 64, j0 = ji * 64;
    const int wv = tid >> 6, lane = tid & 63;
    const int qg = wv >> 1, jg = wv & 1;
    const int lrow = lane & 31, kg = lane >> 5;

    // hoist Q fragments (A-operand): row = l&31, 8 bf16 at k = ks*16 + (l>>5)*8
    short8 qh[4], ql[4];
    {
        const size_t qoff = ((size_t)d * Q_ + q0 + qg * 32 + lrow) * F_ + kg * 8;
#pragma unroll
        for (int ks = 0; ks < 4; ++ks) {
            qh[ks] = *(const short8*)(qhi + qoff + ks * 16);
            ql[ks] = *(const short8*)(qlo + qoff + ks * 16);
        }
    }

    float m1[16], m2[16]; int b1[16];
#pragma unroll
    for (int r = 0; r < 16; ++r) { m1[r] = -3e38f; m2[r] = -3e38f; b1[r] = 0; }

    const int nsteps = BS_ / SPLIT_;       // 64
    const int bstart = half * nsteps;
    const int kstride = NB_ * F_;          // shorts per bucket step
    const int sr = tid >> 3, sc = (tid & 7) * 8;   // staging dest row/col

    const short* cph = khi + (size_t)d * DB_ * F_ + ((size_t)bstart * NB_ + j0) * F_;
    const short* cpl = klo + (size_t)d * DB_ * F_ + ((size_t)bstart * NB_ + j0) * F_;

    { // prologue: stage tile bstart into buf 0
        short8 h0 = *(const short8*)(cph + (size_t)tid * 8);
        short8 h1 = *(const short8*)(cph + (size_t)(tid + 256) * 8);
        short8 l0 = *(const short8*)(cpl + (size_t)tid * 8);
        short8 l1 = *(const short8*)(cpl + (size_t)(tid + 256) * 8);
        *(short8*)&kbuf[0][0][sr][sc]      = h0;
        *(short8*)&kbuf[0][0][sr + 32][sc] = h1;
        *(short8*)&kbuf[0][1][sr][sc]      = l0;
        *(short8*)&kbuf[0][1][sr + 32][sc] = l1;
    }
    __syncthreads();

    const int jrow = jg * 32 + lrow;
    int cur = 0;
    for (int bb = 0; bb < nsteps; ++bb) {
        const int b = bstart + bb;
        // branchless clamped prefetch of next tile (last iter reloads same)
        const short* nph = (bb + 1 < nsteps) ? cph + kstride : cph;
        const short* npl = (bb + 1 < nsteps) ? cpl + kstride : cpl;
        short8 h0 = *(const short8*)(nph + (size_t)tid * 8);
        short8 h1 = *(const short8*)(nph + (size_t)(tid + 256) * 8);
        short8 l0 = *(const short8*)(npl + (size_t)tid * 8);
        short8 l1 = *(const short8*)(npl + (size_t)(tid + 256) * 8);
        cph = nph; cpl = npl;

        short8 kh[4], kl[4];
#pragma unroll
        for (int ks = 0; ks < 4; ++ks) {
            kh[ks] = *(const short8*)&kbuf[cur][0][jrow][ks * 16 + kg * 8];
            kl[ks] = *(const short8*)&kbuf[cur][1][jrow][ks * 16 + kg * 8];
        }
        f32x16 c0 = {0,0,0,0,0,0,0,0,0,0,0,0,0,0,0,0};
        f32x16 c1 = {0,0,0,0,0,0,0,0,0,0,0,0,0,0,0,0};
#pragma unroll
        for (int ks = 0; ks < 4; ++ks) c0 = mfma32(qh[ks], kh[ks], c0);
#pragma unroll
        for (int ks = 0; ks < 4; ++ks) c1 = mfma32(qh[ks], kl[ks], c1);
#pragma unroll
        for (int ks = 0; ks < 4; ++ks) c0 = mfma32(ql[ks], kh[ks], c0);

        // branchless top-2: med3 computes the new 2nd-max in ONE instruction
#pragma unroll
        for (int r = 0; r < 16; ++r) {
            float v = c0[r] + c1[r];
            b1[r] = (v > m1[r]) ? b : b1[r];
            m2[r] = __builtin_amdgcn_fmed3f(v, m1[r], m2[r]);
            m1[r] = fmaxf(m1[r], v);
        }

        const int nb2 = cur ^ 1;
        *(short8*)&kbuf[nb2][0][sr][sc]      = h0;
        *(short8*)&kbuf[nb2][0][sr + 32][sc] = h1;
        *(short8*)&kbuf[nb2][1][sr][sc]      = l0;
        *(short8*)&kbuf[nb2][1][sr + 32][sc] = l1;
        __syncthreads();
        cur ^= 1;
    }

    // write partials; C layout (verified): col=lane&31, row=(r&3)+8*(r>>2)+4*kg
#pragma unroll
    for (int r = 0; r < 16; ++r) {
        const int q = q0 + qg * 32 + 4 * kg + (r & 3) + 8 * (r >> 2);
        const size_t t = (((size_t)q * D_ + d) << 7) + j0 + jrow;
        const size_t p = (size_t)half * NT_ + t;
        m1p[p] = m1[r]; m2p[p] = m2[r]; b1p[p] = b1[r];
    }
}

// ---------------------------------------------------------------------------
// Merge split-b partials -> final argmax index + near-tie flag list.
// ---------------------------------------------------------------------------
__global__ void k_merge(const float* __restrict__ m1p, const float* __restrict__ m2p,
                        const int* __restrict__ b1p, int* __restrict__ idx0,
                        int* __restrict__ flag_cnt, int* __restrict__ flag_list)
{
    int t = blockIdx.x * 256 + threadIdx.x;
    if (t >= NT_) return;
    float m1 = -3e38f, m2 = -3e38f;
    int i1 = 0;
#pragma unroll
    for (int h = 0; h < SPLIT_; ++h) {
        float a    = m1p[(size_t)h * NT_ + t];
        float bsec = m2p[(size_t)h * NT_ + t];
        int   ib   = b1p[(size_t)h * NT_ + t];
        if (a > m1) { m2 = m1; m1 = a; i1 = ib; }
        else if (a > m2) m2 = a;
        if (bsec > m2) m2 = bsec;
    }
    idx0[t] = i1;
    if (m2 >= m1 - MARGIN_) {
        int pos = atomicAdd(flag_cnt, 1);
        if (pos < NT_) flag_list[pos] = t;
    }
}

// ---------------------------------------------------------------------------
// K2: gather. Writes all 512 MB of output (hard-argmax rows).
// ---------------------------------------------------------------------------
__global__ void k_gather(const float* __restrict__ key_db, const float* __restrict__ value_db,
                         const int* __restrict__ idx0, float4* __restrict__ out)
{
    const int total = NT_ * 16 * 2;   // 33,554,432 float4
    for (int e = blockIdx.x * 256 + threadIdx.x; e < total; e += gridDim.x * 256) {
        int half = e >> 24;
        int rem  = e & 0xFFFFFF;
        int t  = rem >> 4;
        int fc = rem & 15;
        int j = t & 127;
        int d = (t >> 7) & 7;
        int b = idx0[t];
        const float* db = half ? value_db : key_db;
        int n = b * NB_ + j;
        out[e] = *reinterpret_cast<const float4*>(db + ((size_t)d * DB_ + n) * F_ + fc * 4);
    }
}

// ---------------------------------------------------------------------------
// K3: exact fp64 fix-up for flagged near-tie triples. One wave per triple.
// ---------------------------------------------------------------------------
__global__ void k_fix(const float* __restrict__ query, const float* __restrict__ key_db,
                      const float* __restrict__ value_db, const int* __restrict__ flag_cnt,
                      const int* __restrict__ flag_list, float* __restrict__ out)
{
    int cnt = *flag_cnt;
    if (cnt > NT_) cnt = NT_;
    int gw   = (blockIdx.x * blockDim.x + threadIdx.x) >> 6;
    int lane = threadIdx.x & 63;
    int nw   = (gridDim.x * blockDim.x) >> 6;

    for (int w = gw; w < cnt; w += nw) {
        int t = flag_list[w];
        int j = t & 127, d = (t >> 7) & 7, qi = t >> 10;
        const float* qrow = query + ((size_t)qi * D_ + d) * F_;
        const float* kb = key_db + (size_t)d * DB_ * F_;
        const float* vb = value_db + (size_t)d * DB_ * F_;

        double sv[4];
#pragma unroll
        for (int i = 0; i < 4; ++i) {
            int b = lane * 4 + i;
            const float* krow = kb + ((size_t)b * NB_ + j) * F_;
            double a = 0.0;
            for (int k2 = 0; k2 < F_; ++k2) a += (double)qrow[k2] * (double)krow[k2];
            sv[i] = a;
        }
        double m = fmax(fmax(sv[0], sv[1]), fmax(sv[2], sv[3]));
        for (int off = 32; off; off >>= 1) m = fmax(m, __shfl_xor(m, off));
        double ev[4];
        double es = 0.0;
#pragma unroll
        for (int i = 0; i < 4; ++i) { ev[i] = exp((sv[i] - m) * 1e6); es += ev[i]; }
        for (int off = 32; off; off >>= 1) es += __shfl_xor(es, off);
        double inv = 1.0 / es;
#pragma unroll
        for (int i = 0; i < 4; ++i) ev[i] *= inv;

        double ak = 0.0, av = 0.0;
        for (int src = 0; src < 64; ++src) {
#pragma unroll
            for (int i = 0; i < 4; ++i) {
                double wv = __shfl(ev[i], src);
                if (wv != 0.0) {
                    int b = src * 4 + i;
                    size_t o = ((size_t)b * NB_ + j) * F_ + lane;
                    ak += wv * (double)kb[o];
                    av += wv * (double)vb[o];
                }
            }
        }
        out[(size_t)t * F_ + lane] = (float)ak;
        out[(size_t)NT_ * F_ + (size_t)t * F_ + lane] = (float)av;
    }
}

// ---------------------------------------------------------------------------
extern "C" void kernel_launch(void* const* d_in, const int* in_sizes, int n_in,
                              void* d_out, int out_size, void* d_ws, size_t ws_size,
                              hipStream_t stream)
{
    const float* query    = (const float*)d_in[0];
    const float* key_db   = (const float*)d_in[1];
    const float* value_db = (const float*)d_in[2];
    float* out = (float*)d_out;

    // ws layout (~8.4 MB): idx0[NT] | flag_cnt | flag_list[NT]
    int* idx0      = (int*)d_ws;
    int* flag_cnt  = (int*)((char*)d_ws + (size_t)NT_ * 4);
    int* flag_list = (int*)((char*)d_ws + (size_t)NT_ * 4 + 256);

    // Scratch parked in the not-yet-written front of d_out (~117 MB of 512 MB):
    // bf16 hi/lo copies of keys+queries, then split-b partials. k_gather
    // overwrites every byte of d_out afterwards; all reads happen before.
    short* khi = (short*)d_out;                          // 33.5 MB
    short* klo = khi + (size_t)D_ * DB_ * F_;            // 33.5 MB
    short* qhi = klo + (size_t)D_ * DB_ * F_;            // 1 MB
    short* qlo = qhi + (size_t)Q_ * D_ * F_;             // 1 MB
    float* m1p = (float*)(qlo + (size_t)Q_ * D_ * F_);   // 16 MB
    float* m2p = m1p + (size_t)SPLIT_ * NT_;             // 16 MB
    int*   b1p = (int*)(m2p + (size_t)SPLIT_ * NT_);     // 16 MB

    hipMemsetAsync(flag_cnt, 0, 4, stream);

    k_conv     <<<2048, 256, 0, stream>>>(key_db, khi, klo, D_ * DB_ * F_ / 4);
    k_convq    <<<512,  256, 0, stream>>>(query, qhi, qlo);
    k_scan_mfma<<<1024, 256, 0, stream>>>(khi, klo, qhi, qlo, m1p, m2p, b1p);
    k_merge    <<<NT_ / 256, 256, 0, stream>>>(m1p, m2p, b1p, idx0, flag_cnt, flag_list);
    k_gather   <<<2048, 256, 0, stream>>>(key_db, value_db, idx0, (float4*)d_out);
    k_fix      <<<256,  256, 0, stream>>>(query, key_db, value_db, flag_cnt, flag_list, out);
}